// Round 4
// baseline (101.288 us; speedup 1.0000x reference)
//
#include <hip/hip_runtime.h>
#include <hip/hip_bf16.h>

typedef unsigned int u32;
typedef unsigned short u16;
typedef __bf16 bf16x8 __attribute__((ext_vector_type(8)));
typedef float f32x4 __attribute__((ext_vector_type(4)));

#define N_SPATIAL 4096
#define K_SEL 409
#define NBATCH 32
#define NCHAN 256
#define NTILE2 3    // 128x128 upper-tri tiles of 2x2 grid: (0,0),(0,1),(1,1)
#define NKSP 8      // K-split

__constant__ int c2_TI[NTILE2] = {0,0,1};
__constant__ int c2_TJ[NTILE2] = {0,1,1};

__device__ __forceinline__ u16 f2bf(float f) {
    __hip_bfloat16 h = __float2bfloat16(f);
    return *reinterpret_cast<u16*>(&h);
}

__device__ __forceinline__ void gload_lds16(const void* g, void* l) {
    __builtin_amdgcn_global_load_lds((const __attribute__((address_space(1))) void*)g,
                                     (__attribute__((address_space(3))) void*)l, 16, 0, 0);
}

// ---------------- Kernel A: per-row exact top-k threshold + sparsify to bf16 ----------------
__global__ __launch_bounds__(256) void topk_sparsify(const float* __restrict__ x,
                                                     u16* __restrict__ Fout) {
    __shared__ u32 hist[2048];
    __shared__ u32 waveSum[4];
    __shared__ u32 sh_pref, sh_krem;

    const int t = threadIdx.x;
    const int lane = t & 63;
    const int wid = t >> 6;
    const int row = blockIdx.x;
    const float* xr = x + (size_t)row * N_SPATIAL;

    float4 v[4];
#pragma unroll
    for (int j = 0; j < 4; ++j)
        v[j] = reinterpret_cast<const float4*>(xr)[t + 256 * j];

    u32 pref = 0, krem = K_SEL;
    const int shifts[3] = {21, 10, 0};
    const int nbits[3]  = {11, 11, 10};

#pragma unroll
    for (int p = 0; p < 3; ++p) {
        const int shift = shifts[p];
        const int bins = 1 << nbits[p];
        const int mshift = (p == 0) ? 31 : shifts[p - 1];

        for (int i = t; i < bins; i += 256) hist[i] = 0;
        __syncthreads();

#pragma unroll
        for (int j = 0; j < 4; ++j) {
            const float* vf = reinterpret_cast<const float*>(&v[j]);
#pragma unroll
            for (int e = 0; e < 4; ++e) {
                u32 key = __float_as_uint(vf[e]) & 0x7fffffffu;
                if (p == 0 || ((key >> mshift) == pref))
                    atomicAdd(&hist[(key >> shift) & (bins - 1)], 1u);
            }
        }
        __syncthreads();

        const int bpt = bins / 256;
        const int base = t * bpt;
        u32 hloc[8];
        u32 csum = 0;
#pragma unroll
        for (int j = 0; j < 8; ++j) {
            if (j < bpt) { hloc[j] = hist[base + j]; csum += hloc[j]; }
        }
        u32 s = csum;
#pragma unroll
        for (int d = 1; d < 64; d <<= 1) {
            u32 o = __shfl_down(s, d);
            if (lane + d < 64) s += o;
        }
        if (lane == 0) waveSum[wid] = s;
        __syncthreads();
        u32 above = s - csum;
        for (int w2 = wid + 1; w2 < 4; ++w2) above += waveSum[w2];

        u32 cum = above;
#pragma unroll
        for (int j = 7; j >= 0; --j) {
            if (j < bpt) {
                u32 c = hloc[j];
                if (cum < krem && cum + c >= krem) {
                    sh_pref = (pref << nbits[p]) | (u32)(base + j);
                    sh_krem = krem - cum;
                }
                cum += c;
            }
        }
        __syncthreads();
        pref = sh_pref;
        krem = sh_krem;
        __syncthreads();
    }

    const u32 thr = pref;
    const size_t obase = (size_t)row * N_SPATIAL;
#pragma unroll
    for (int j = 0; j < 4; ++j) {
        const float* vf = reinterpret_cast<const float*>(&v[j]);
        ushort4 o;
        u16* op = reinterpret_cast<u16*>(&o);
#pragma unroll
        for (int e = 0; e < 4; ++e) {
            u32 key = __float_as_uint(vf[e]) & 0x7fffffffu;
            float f = (key >= thr) ? vf[e] : 0.0f;
            op[e] = f2bf(f);
        }
        *reinterpret_cast<ushort4*>(Fout + obase + 4 * t + 1024 * j) = o;
    }
}

// ---------------- Kernel B: m97-structure gram partial ----------------
// 128x128 tile, 4 waves x (4x4 frags), single-buffered LDS (32 KiB), 2 barriers/K-step.
// 768 blocks = 32 batches x 3 upper-tri tiles x 8 K-splits = exactly 3 blocks/CU.
__global__ __launch_bounds__(256) void gram_partial(const u16* __restrict__ F,
                                                    float* __restrict__ pg) {
    __shared__ __align__(16) u16 As[128 * 64];
    __shared__ __align__(16) u16 Bs[128 * 64];

    const int t = threadIdx.x;
    const int lane = t & 63;
    const int wid = t >> 6;

    const int bid = blockIdx.x;
    const int xcd = bid & 7;
    const int idx = bid >> 3;           // 0..95
    const int b = (idx / 24) * 8 + xcd; // same-batch blocks share an XCD
    const int sub = idx % 24;
    const int tile = sub >> 3;          // 0..2
    const int ksp = sub & 7;            // 0..7
    const int ti = c2_TI[tile], tj = c2_TJ[tile];
    const bool diag = (ti == tj);
    const int kbase = ksp * 512;

    const u16* Fb = F + (size_t)b * NCHAN * N_SPATIAL;
    const int wr = wid >> 1, wc = wid & 1;   // wave's 64x64 quadrant of the 128x128 tile

    // staging: 4 issues/matrix/thread; chunk c=q*256+t in [0,1024); row=c>>3, dst chunk=c&7
    // LDS[row][s] holds global chunk s^(row&7)  (XOR swizzle, both-sides — rule #21)
    const u16* gA[4];
    const u16* gB[4];
#pragma unroll
    for (int q = 0; q < 4; ++q) {
        const int c = q * 256 + t;
        const int r = c >> 3;
        const int sc = ((c & 7) ^ (r & 7)) * 8;
        gA[q] = Fb + (size_t)(ti * 128 + r) * N_SPATIAL + kbase + sc;
        gB[q] = Fb + (size_t)(tj * 128 + r) * N_SPATIAL + kbase + sc;
    }

    f32x4 acc[4][4] = {};

    for (int kk = 0; kk < 8; ++kk) {        // K=512 per block, BK=64
        const int kb = kk * 64;
#pragma unroll
        for (int q = 0; q < 4; ++q) {
            gload_lds16(gA[q] + kb, As + (q * 256 + t) * 8);
            if (!diag) gload_lds16(gB[q] + kb, Bs + (q * 256 + t) * 8);
        }
        __syncthreads();                    // vmcnt(0) drain: staged data visible

        const u16* Bb = diag ? As : Bs;
#pragma unroll
        for (int ks = 0; ks < 2; ++ks) {
            const int kc0 = ks * 4 + (lane >> 4);
            bf16x8 a[4], bb[4];
#pragma unroll
            for (int m = 0; m < 4; ++m) {
                const int r = wr * 64 + m * 16 + (lane & 15);
                a[m] = *reinterpret_cast<const bf16x8*>(As + r * 64 + ((kc0 ^ (r & 7)) * 8));
            }
#pragma unroll
            for (int n = 0; n < 4; ++n) {
                const int r = wc * 64 + n * 16 + (lane & 15);
                bb[n] = *reinterpret_cast<const bf16x8*>(Bb + r * 64 + ((kc0 ^ (r & 7)) * 8));
            }
#pragma unroll
            for (int m = 0; m < 4; ++m)
#pragma unroll
                for (int n = 0; n < 4; ++n)
                    acc[m][n] = __builtin_amdgcn_mfma_f32_16x16x32_bf16(a[m], bb[n], acc[m][n], 0, 0, 0);
        }
        __syncthreads();                    // all waves done reading before next stage
    }

    // write 128x128 fp32 partial tile
    float* pt = pg + ((size_t)(b * NTILE2 + tile) * NKSP + ksp) * 16384;
#pragma unroll
    for (int m = 0; m < 4; ++m)
#pragma unroll
        for (int n = 0; n < 4; ++n) {
            const int col = wc * 64 + n * 16 + (lane & 15);
#pragma unroll
            for (int r = 0; r < 4; ++r) {
                const int rowi = wr * 64 + m * 16 + (lane >> 4) * 4 + r;
                pt[rowi * 128 + col] = acc[m][n][r];
            }
        }
}

// ---------------- Kernel C: combine 8 K-split partials + fused loss (w/ mirror) ----------------
__global__ __launch_bounds__(256) void combine_loss(const float* __restrict__ pg,
                                                    const float* __restrict__ T,
                                                    float* __restrict__ partials) {
    __shared__ float Gs[64][65];
    __shared__ float red[4];

    const int t = threadIdx.x;
    const int lane = t & 63;
    const int wid = t >> 6;
    const int bid = blockIdx.x;            // 0..95
    const int b = bid / NTILE2, tile = bid % NTILE2;
    const int ti = c2_TI[tile], tj = c2_TJ[tile];
    const bool diag = (ti == tj);
    const float invNorm = 1.0f / 33554432.0f;

    const float* p = pg + (size_t)(b * NTILE2 + tile) * NKSP * 16384;
    const float* Tb = T + (size_t)b * (NCHAN * NCHAN);

    float s = 0.f;
#pragma unroll
    for (int q = 0; q < 4; ++q) {          // 64x64 quadrants of the 128x128 tile
        const int qr = q >> 1, qc = q & 1;
#pragma unroll
        for (int j = 0; j < 16; ++j) {
            const int e = j * 256 + t, r = e >> 6, c = e & 63;
            const int gi = (qr * 64 + r) * 128 + qc * 64 + c;
            float G = 0.f;
#pragma unroll
            for (int sl = 0; sl < NKSP; ++sl) G += p[gi + sl * 16384];
            G *= invNorm;
            const float d = Tb[(ti * 128 + qr * 64 + r) * NCHAN + (tj * 128 + qc * 64 + c)] - G;
            s += d * d;
            if (!diag) Gs[r][c] = G;
        }
        if (!diag) {
            __syncthreads();
#pragma unroll
            for (int j = 0; j < 16; ++j) {
                const int e = j * 256 + t, r = e >> 6, c = e & 63;
                const float d = Tb[(tj * 128 + qc * 64 + r) * NCHAN + (ti * 128 + qr * 64 + c)] - Gs[c][r];
                s += d * d;
            }
            __syncthreads();               // Gs safe to overwrite next quadrant
        }
    }
#pragma unroll
    for (int dd = 32; dd >= 1; dd >>= 1) s += __shfl_down(s, dd);
    if (lane == 0) red[wid] = s;
    __syncthreads();
    if (t == 0) partials[bid] = red[0] + red[1] + red[2] + red[3];
}

// ---------------- Kernel D: deterministic final reduction over 96 partials ----------------
__global__ __launch_bounds__(256) void final_reduce(const float* __restrict__ partials,
                                                    float* __restrict__ out) {
    __shared__ float red[4];
    const int t = threadIdx.x;
    const int lane = t & 63;
    const int wid = t >> 6;
    float s = (t < 96) ? partials[t] : 0.0f;
#pragma unroll
    for (int dd = 32; dd >= 1; dd >>= 1) s += __shfl_down(s, dd);
    if (lane == 0) red[wid] = s;
    __syncthreads();
    if (t == 0) out[0] = (red[0] + red[1] + red[2] + red[3]) * (1.0e9f / 2097152.0f);
}

extern "C" void kernel_launch(void* const* d_in, const int* in_sizes, int n_in,
                              void* d_out, int out_size, void* d_ws, size_t ws_size,
                              hipStream_t stream) {
    const float* x  = (const float*)d_in[0];           // (32,256,64,64) fp32
    const float* tg = (const float*)d_in[1];           // (32,256,256) fp32
    float* out = (float*)d_out;

    // ws layout: [0,4KiB) partials (96 f32); [4KiB, +48MiB) partial-G; then F (64 MiB)
    float* partials = (float*)d_ws;
    float* pg = (float*)((char*)d_ws + 4096);
    u16* F = (u16*)((char*)d_ws + 4096 + (size_t)NBATCH * NTILE2 * NKSP * 16384 * 4);

    topk_sparsify<<<NBATCH * NCHAN, 256, 0, stream>>>(x, F);
    gram_partial<<<NBATCH * NTILE2 * NKSP, 256, 0, stream>>>(F, pg);
    combine_loss<<<NBATCH * NTILE2, 256, 0, stream>>>(pg, tg, partials);
    final_reduce<<<1, 256, 0, stream>>>(partials, out);
}

// Round 5
// 82.247 us; speedup vs baseline: 1.2315x; 1.2315x over previous
//
#include <hip/hip_runtime.h>
#include <hip/hip_bf16.h>

typedef unsigned int u32;
typedef unsigned short u16;
typedef __bf16 bf16x8 __attribute__((ext_vector_type(8)));
typedef float f32x4 __attribute__((ext_vector_type(4)));

#define N_SPATIAL 4096
#define K_SEL 409
#define NBATCH 32
#define NCHAN 256
#define NTILE2 3    // 128x128 upper-tri tiles of 2x2 grid: (0,0),(0,1),(1,1)
#define NKSP 4      // K-split (K=1024 per block)

__constant__ int c2_TI[NTILE2] = {0,0,1};
__constant__ int c2_TJ[NTILE2] = {0,1,1};

__device__ __forceinline__ u16 f2bf(float f) {
    __hip_bfloat16 h = __float2bfloat16(f);
    return *reinterpret_cast<u16*>(&h);
}

__device__ __forceinline__ void gload_lds16(const void* g, void* l) {
    __builtin_amdgcn_global_load_lds((const __attribute__((address_space(1))) void*)g,
                                     (__attribute__((address_space(3))) void*)l, 16, 0, 0);
}

// ---------------- Kernel A: per-row exact top-k threshold + sparsify to bf16 ----------------
__global__ __launch_bounds__(256) void topk_sparsify(const float* __restrict__ x,
                                                     u16* __restrict__ Fout) {
    __shared__ u32 hist[2048];
    __shared__ u32 waveSum[4];
    __shared__ u32 sh_pref, sh_krem;

    const int t = threadIdx.x;
    const int lane = t & 63;
    const int wid = t >> 6;
    const int row = blockIdx.x;
    const float* xr = x + (size_t)row * N_SPATIAL;

    float4 v[4];
#pragma unroll
    for (int j = 0; j < 4; ++j)
        v[j] = reinterpret_cast<const float4*>(xr)[t + 256 * j];

    u32 pref = 0, krem = K_SEL;
    const int shifts[3] = {21, 10, 0};
    const int nbits[3]  = {11, 11, 10};

#pragma unroll
    for (int p = 0; p < 3; ++p) {
        const int shift = shifts[p];
        const int bins = 1 << nbits[p];
        const int mshift = (p == 0) ? 31 : shifts[p - 1];

        for (int i = t; i < bins; i += 256) hist[i] = 0;
        __syncthreads();

#pragma unroll
        for (int j = 0; j < 4; ++j) {
            const float* vf = reinterpret_cast<const float*>(&v[j]);
#pragma unroll
            for (int e = 0; e < 4; ++e) {
                u32 key = __float_as_uint(vf[e]) & 0x7fffffffu;
                if (p == 0 || ((key >> mshift) == pref))
                    atomicAdd(&hist[(key >> shift) & (bins - 1)], 1u);
            }
        }
        __syncthreads();

        const int bpt = bins / 256;
        const int base = t * bpt;
        u32 hloc[8];
        u32 csum = 0;
#pragma unroll
        for (int j = 0; j < 8; ++j) {
            if (j < bpt) { hloc[j] = hist[base + j]; csum += hloc[j]; }
        }
        u32 s = csum;
#pragma unroll
        for (int d = 1; d < 64; d <<= 1) {
            u32 o = __shfl_down(s, d);
            if (lane + d < 64) s += o;
        }
        if (lane == 0) waveSum[wid] = s;
        __syncthreads();
        u32 above = s - csum;
        for (int w2 = wid + 1; w2 < 4; ++w2) above += waveSum[w2];

        u32 cum = above;
#pragma unroll
        for (int j = 7; j >= 0; --j) {
            if (j < bpt) {
                u32 c = hloc[j];
                if (cum < krem && cum + c >= krem) {
                    sh_pref = (pref << nbits[p]) | (u32)(base + j);
                    sh_krem = krem - cum;
                }
                cum += c;
            }
        }
        __syncthreads();
        pref = sh_pref;
        krem = sh_krem;
        __syncthreads();
    }

    const u32 thr = pref;
    const size_t obase = (size_t)row * N_SPATIAL;
#pragma unroll
    for (int j = 0; j < 4; ++j) {
        const float* vf = reinterpret_cast<const float*>(&v[j]);
        ushort4 o;
        u16* op = reinterpret_cast<u16*>(&o);
#pragma unroll
        for (int e = 0; e < 4; ++e) {
            u32 key = __float_as_uint(vf[e]) & 0x7fffffffu;
            float f = (key >= thr) ? vf[e] : 0.0f;
            op[e] = f2bf(f);
        }
        *reinterpret_cast<ushort4*>(Fout + obase + 4 * t + 1024 * j) = o;
    }
}

// ---------------- Kernel B: 128x128 symmetric gram, K-split 4, 2-phase dbuf ----------------
// 384 blocks = 32 batches x 3 tiles x 4 K-splits; 64 KiB LDS -> 2 blocks/CU, all resident.
__global__ __launch_bounds__(256) void gram_partial(const u16* __restrict__ F,
                                                    float* __restrict__ pg) {
    __shared__ __align__(16) u16 As[2][128 * 64];   // 32 KiB
    __shared__ __align__(16) u16 Bs[2][128 * 64];   // 32 KiB

    const int t = threadIdx.x;
    const int lane = t & 63;
    const int wid = t >> 6;

    const int bid = blockIdx.x;
    const int xcd = bid & 7;
    const int idx = bid >> 3;           // 0..47
    const int b = (idx / 12) * 8 + xcd; // same-batch blocks share an XCD
    const int sub = idx % 12;
    const int tile = sub >> 2;          // 0..2
    const int ksp = sub & 3;            // 0..3
    const int ti = c2_TI[tile], tj = c2_TJ[tile];
    const bool diag = (ti == tj);
    const int kbase = ksp * 1024;

    const u16* Fb = F + (size_t)b * NCHAN * N_SPATIAL;
    const int wr = wid >> 1, wc = wid & 1;   // wave's 64x64 quadrant

    // staging geometry (correctness-proven in round 4): chunk c=q*256+t; row=c>>3;
    // LDS[row][s] holds global chunk s^(row&7)  (XOR swizzle both sides — rule #21)
    const u16* gA[4];
    const u16* gB[4];
#pragma unroll
    for (int q = 0; q < 4; ++q) {
        const int c = q * 256 + t;
        const int r = c >> 3;
        const int sc = ((c & 7) ^ (r & 7)) * 8;
        gA[q] = Fb + (size_t)(ti * 128 + r) * N_SPATIAL + kbase + sc;
        gB[q] = Fb + (size_t)(tj * 128 + r) * N_SPATIAL + kbase + sc;
    }

    f32x4 acc[4][4] = {};
    const int NKK = 16;                 // K=1024, BK=64

    // prologue: stage K-step 0 into buffer 0
#pragma unroll
    for (int q = 0; q < 4; ++q) {
        gload_lds16(gA[q], &As[0][(q * 256 + t) * 8]);
        if (!diag) gload_lds16(gB[q], &Bs[0][(q * 256 + t) * 8]);
    }
    __syncthreads();

    int cur = 0;
    for (int kk = 0; kk < NKK; ++kk) {
        // 2-phase: issue next K-step's staging BEFORE compute (T3-minimum recipe)
        if (kk + 1 < NKK) {
            const int kb = (kk + 1) * 64;
#pragma unroll
            for (int q = 0; q < 4; ++q) {
                gload_lds16(gA[q] + kb, &As[cur ^ 1][(q * 256 + t) * 8]);
                if (!diag) gload_lds16(gB[q] + kb, &Bs[cur ^ 1][(q * 256 + t) * 8]);
            }
        }

        const u16* Ab = &As[cur][0];
        const u16* Bb = diag ? &As[cur][0] : &Bs[cur][0];
#pragma unroll
        for (int ks = 0; ks < 2; ++ks) {
            const int kc0 = ks * 4 + (lane >> 4);
            bf16x8 a[4], bb[4];
#pragma unroll
            for (int m = 0; m < 4; ++m) {
                const int r = wr * 64 + m * 16 + (lane & 15);
                a[m] = *reinterpret_cast<const bf16x8*>(Ab + r * 64 + ((kc0 ^ (r & 7)) * 8));
            }
#pragma unroll
            for (int n = 0; n < 4; ++n) {
                const int r = wc * 64 + n * 16 + (lane & 15);
                bb[n] = *reinterpret_cast<const bf16x8*>(Bb + r * 64 + ((kc0 ^ (r & 7)) * 8));
            }
#pragma unroll
            for (int m = 0; m < 4; ++m)
#pragma unroll
                for (int n = 0; n < 4; ++n)
                    acc[m][n] = __builtin_amdgcn_mfma_f32_16x16x32_bf16(a[m], bb[n], acc[m][n], 0, 0, 0);
        }
        __syncthreads();   // drains vmcnt(0): next buffer staged; all waves done with cur
        cur ^= 1;
    }

    // write 128x128 fp32 partial tile
    float* pt = pg + ((size_t)(b * NTILE2 + tile) * NKSP + ksp) * 16384;
#pragma unroll
    for (int m = 0; m < 4; ++m)
#pragma unroll
        for (int n = 0; n < 4; ++n) {
            const int col = wc * 64 + n * 16 + (lane & 15);
#pragma unroll
            for (int r = 0; r < 4; ++r) {
                const int rowi = wr * 64 + m * 16 + (lane >> 4) * 4 + r;
                pt[rowi * 128 + col] = acc[m][n][r];
            }
        }
}

// ---------------- Kernel C: combine 4 K-partials + fused loss with mirror ----------------
// 384 blocks = 32 batches x 3 tiles x 4 row-quarters (32 rows each).
__global__ __launch_bounds__(256) void combine_loss(const float* __restrict__ pg,
                                                    const float* __restrict__ T,
                                                    float* __restrict__ partials) {
    __shared__ float Gs[128][33];   // [col][row-within-quarter], padded
    __shared__ float red[4];

    const int t = threadIdx.x;
    const int lane = t & 63;
    const int wid = t >> 6;
    const int bid = blockIdx.x;            // 0..383
    const int b = bid / (NTILE2 * 4);
    const int rest = bid % (NTILE2 * 4);
    const int tile = rest >> 2;
    const int qtr = rest & 3;              // row quarter
    const int ti = c2_TI[tile], tj = c2_TJ[tile];
    const bool diag = (ti == tj);
    const float invNorm = 1.0f / 33554432.0f;

    const float* p = pg + (size_t)(b * NTILE2 + tile) * NKSP * 16384 + qtr * 4096;
    const float* Tb = T + (size_t)b * (NCHAN * NCHAN);

    float s = 0.f;
#pragma unroll
    for (int j = 0; j < 16; ++j) {
        const int e = j * 256 + t;
        const int r = e >> 7, c = e & 127;         // r in [0,32)
        float G = p[e] + p[e + 16384] + p[e + 2 * 16384] + p[e + 3 * 16384];
        G *= invNorm;
        const float d = Tb[(ti * 128 + qtr * 32 + r) * NCHAN + tj * 128 + c] - G;
        s += d * d;
        if (!diag) Gs[c][r] = G;
    }
    if (!diag) {
        __syncthreads();
#pragma unroll
        for (int j = 0; j < 16; ++j) {
            const int m = j * 256 + t;
            const int rr = m & 31, cc = m >> 5;    // cc in [0,128)
            const float d = Tb[(tj * 128 + cc) * NCHAN + ti * 128 + qtr * 32 + rr] - Gs[cc][rr];
            s += d * d;
        }
    }
#pragma unroll
    for (int dd = 32; dd >= 1; dd >>= 1) s += __shfl_down(s, dd);
    if (lane == 0) red[wid] = s;
    __syncthreads();
    if (t == 0) partials[bid] = red[0] + red[1] + red[2] + red[3];
}

// ---------------- Kernel D: deterministic final reduction over 384 partials ----------------
__global__ __launch_bounds__(256) void final_reduce(const float* __restrict__ partials,
                                                    float* __restrict__ out) {
    __shared__ float red[4];
    const int t = threadIdx.x;
    const int lane = t & 63;
    const int wid = t >> 6;
    float s = partials[t] + ((t < 128) ? partials[256 + t] : 0.0f);
#pragma unroll
    for (int dd = 32; dd >= 1; dd >>= 1) s += __shfl_down(s, dd);
    if (lane == 0) red[wid] = s;
    __syncthreads();
    if (t == 0) out[0] = (red[0] + red[1] + red[2] + red[3]) * (1.0e9f / 2097152.0f);
}

extern "C" void kernel_launch(void* const* d_in, const int* in_sizes, int n_in,
                              void* d_out, int out_size, void* d_ws, size_t ws_size,
                              hipStream_t stream) {
    const float* x  = (const float*)d_in[0];           // (32,256,64,64) fp32
    const float* tg = (const float*)d_in[1];           // (32,256,256) fp32
    float* out = (float*)d_out;

    // ws layout: [0,4KiB) partials (384 f32); [4KiB, +24MiB) partial-G; then F (64 MiB)
    float* partials = (float*)d_ws;
    float* pg = (float*)((char*)d_ws + 4096);
    u16* F = (u16*)((char*)d_ws + 4096 + (size_t)NBATCH * NTILE2 * NKSP * 16384 * 4);

    topk_sparsify<<<NBATCH * NCHAN, 256, 0, stream>>>(x, F);
    gram_partial<<<NBATCH * NTILE2 * NKSP, 256, 0, stream>>>(F, pg);
    combine_loss<<<NBATCH * NTILE2 * 4, 256, 0, stream>>>(pg, tg, partials);
    final_reduce<<<1, 256, 0, stream>>>(partials, out);
}

// Round 6
// 78.043 us; speedup vs baseline: 1.2978x; 1.0539x over previous
//
#include <hip/hip_runtime.h>
#include <hip/hip_bf16.h>

typedef unsigned int u32;
typedef unsigned short u16;
typedef __bf16 bf16x8 __attribute__((ext_vector_type(8)));
typedef float f32x4 __attribute__((ext_vector_type(4)));

#define N_SPATIAL 4096
#define K_SEL 409
#define NBATCH 32
#define NCHAN 256
#define NTILE2 3    // 128x128 upper-tri tiles: (0,0),(0,1),(1,1)
#define NKSP 8      // K-split (K=512 per block) -> 768 blocks = 3/CU exactly

__constant__ int c2_TI[NTILE2] = {0,0,1};
__constant__ int c2_TJ[NTILE2] = {0,1,1};

__device__ __forceinline__ u16 f2bf(float f) {
    __hip_bfloat16 h = __float2bfloat16(f);
    return *reinterpret_cast<u16*>(&h);
}

__device__ __forceinline__ float bf2f(u16 u) {
    __hip_bfloat16 h = *reinterpret_cast<__hip_bfloat16*>(&u);
    return __bfloat162float(h);
}

__device__ __forceinline__ void gload_lds16(const void* g, void* l) {
    __builtin_amdgcn_global_load_lds((const __attribute__((address_space(1))) void*)g,
                                     (__attribute__((address_space(3))) void*)l, 16, 0, 0);
}

// ---------------- Kernel A: per-row exact top-k threshold + sparsify to bf16 ----------------
__global__ __launch_bounds__(256) void topk_sparsify(const float* __restrict__ x,
                                                     u16* __restrict__ Fout) {
    __shared__ u32 hist[2048];
    __shared__ u32 waveSum[4];
    __shared__ u32 sh_pref, sh_krem;

    const int t = threadIdx.x;
    const int lane = t & 63;
    const int wid = t >> 6;
    const int row = blockIdx.x;
    const float* xr = x + (size_t)row * N_SPATIAL;

    float4 v[4];
#pragma unroll
    for (int j = 0; j < 4; ++j)
        v[j] = reinterpret_cast<const float4*>(xr)[t + 256 * j];

    u32 pref = 0, krem = K_SEL;
    const int shifts[3] = {21, 10, 0};
    const int nbits[3]  = {11, 11, 10};

#pragma unroll
    for (int p = 0; p < 3; ++p) {
        const int shift = shifts[p];
        const int bins = 1 << nbits[p];
        const int mshift = (p == 0) ? 31 : shifts[p - 1];

        for (int i = t; i < bins; i += 256) hist[i] = 0;
        __syncthreads();

#pragma unroll
        for (int j = 0; j < 4; ++j) {
            const float* vf = reinterpret_cast<const float*>(&v[j]);
#pragma unroll
            for (int e = 0; e < 4; ++e) {
                u32 key = __float_as_uint(vf[e]) & 0x7fffffffu;
                if (p == 0 || ((key >> mshift) == pref))
                    atomicAdd(&hist[(key >> shift) & (bins - 1)], 1u);
            }
        }
        __syncthreads();

        const int bpt = bins / 256;
        const int base = t * bpt;
        u32 hloc[8];
        u32 csum = 0;
#pragma unroll
        for (int j = 0; j < 8; ++j) {
            if (j < bpt) { hloc[j] = hist[base + j]; csum += hloc[j]; }
        }
        u32 s = csum;
#pragma unroll
        for (int d = 1; d < 64; d <<= 1) {
            u32 o = __shfl_down(s, d);
            if (lane + d < 64) s += o;
        }
        if (lane == 0) waveSum[wid] = s;
        __syncthreads();
        u32 above = s - csum;
        for (int w2 = wid + 1; w2 < 4; ++w2) above += waveSum[w2];

        u32 cum = above;
#pragma unroll
        for (int j = 7; j >= 0; --j) {
            if (j < bpt) {
                u32 c = hloc[j];
                if (cum < krem && cum + c >= krem) {
                    sh_pref = (pref << nbits[p]) | (u32)(base + j);
                    sh_krem = krem - cum;
                }
                cum += c;
            }
        }
        __syncthreads();
        pref = sh_pref;
        krem = sh_krem;
        __syncthreads();
    }

    const u32 thr = pref;
    const size_t obase = (size_t)row * N_SPATIAL;
#pragma unroll
    for (int j = 0; j < 4; ++j) {
        const float* vf = reinterpret_cast<const float*>(&v[j]);
        ushort4 o;
        u16* op = reinterpret_cast<u16*>(&o);
#pragma unroll
        for (int e = 0; e < 4; ++e) {
            u32 key = __float_as_uint(vf[e]) & 0x7fffffffu;
            float f = (key >= thr) ? vf[e] : 0.0f;
            op[e] = f2bf(f);
        }
        *reinterpret_cast<ushort4*>(Fout + obase + 4 * t + 1024 * j) = o;
    }
}

// ---------------- Kernel B: m97-structure gram partial (r4-proven), bf16 pg epilogue ----------------
// 128x128 tile, 4 waves x (4x4 frags), single-buffered 32 KiB LDS, 2 barriers/K-step.
// 768 blocks = 32 batches x 3 upper-tri tiles x 8 K-splits = exactly 3 blocks/CU.
__global__ __launch_bounds__(256) void gram_partial(const u16* __restrict__ F,
                                                    u16* __restrict__ pg) {
    __shared__ __align__(16) u16 As[128 * 64];
    __shared__ __align__(16) u16 Bs[128 * 64];

    const int t = threadIdx.x;
    const int lane = t & 63;
    const int wid = t >> 6;

    const int bid = blockIdx.x;
    const int xcd = bid & 7;
    const int idx = bid >> 3;           // 0..95
    const int b = (idx / 24) * 8 + xcd; // same-batch blocks share an XCD
    const int sub = idx % 24;
    const int tile = sub >> 3;          // 0..2
    const int ksp = sub & 7;            // 0..7
    const int ti = c2_TI[tile], tj = c2_TJ[tile];
    const bool diag = (ti == tj);
    const int kbase = ksp * 512;

    const u16* Fb = F + (size_t)b * NCHAN * N_SPATIAL;
    const int wr = wid >> 1, wc = wid & 1;   // wave's 64x64 quadrant

    // staging: chunk c=q*256+t; row=c>>3; LDS[row][s] holds global chunk s^(row&7)
    const u16* gA[4];
    const u16* gB[4];
#pragma unroll
    for (int q = 0; q < 4; ++q) {
        const int c = q * 256 + t;
        const int r = c >> 3;
        const int sc = ((c & 7) ^ (r & 7)) * 8;
        gA[q] = Fb + (size_t)(ti * 128 + r) * N_SPATIAL + kbase + sc;
        gB[q] = Fb + (size_t)(tj * 128 + r) * N_SPATIAL + kbase + sc;
    }

    f32x4 acc[4][4] = {};

    for (int kk = 0; kk < 8; ++kk) {        // K=512 per block, BK=64
        const int kb = kk * 64;
#pragma unroll
        for (int q = 0; q < 4; ++q) {
            gload_lds16(gA[q] + kb, As + (q * 256 + t) * 8);
            if (!diag) gload_lds16(gB[q] + kb, Bs + (q * 256 + t) * 8);
        }
        __syncthreads();                    // vmcnt(0) drain: staged data visible

        const u16* Bb = diag ? As : Bs;
#pragma unroll
        for (int ks = 0; ks < 2; ++ks) {
            const int kc0 = ks * 4 + (lane >> 4);
            bf16x8 a[4], bb[4];
#pragma unroll
            for (int m = 0; m < 4; ++m) {
                const int r = wr * 64 + m * 16 + (lane & 15);
                a[m] = *reinterpret_cast<const bf16x8*>(As + r * 64 + ((kc0 ^ (r & 7)) * 8));
            }
#pragma unroll
            for (int n = 0; n < 4; ++n) {
                const int r = wc * 64 + n * 16 + (lane & 15);
                bb[n] = *reinterpret_cast<const bf16x8*>(Bb + r * 64 + ((kc0 ^ (r & 7)) * 8));
            }
#pragma unroll
            for (int m = 0; m < 4; ++m)
#pragma unroll
                for (int n = 0; n < 4; ++n)
                    acc[m][n] = __builtin_amdgcn_mfma_f32_16x16x32_bf16(a[m], bb[n], acc[m][n], 0, 0, 0);
        }
        __syncthreads();                    // all waves done reading before next stage
    }

    // write 128x128 bf16 partial tile (partials ~O(10): bf16 err -> G err ~1e-9, negligible)
    u16* pt = pg + ((size_t)(b * NTILE2 + tile) * NKSP + ksp) * 16384;
#pragma unroll
    for (int m = 0; m < 4; ++m)
#pragma unroll
        for (int n = 0; n < 4; ++n) {
            const int col = wc * 64 + n * 16 + (lane & 15);
#pragma unroll
            for (int r = 0; r < 4; ++r) {
                const int rowi = wr * 64 + m * 16 + (lane >> 4) * 4 + r;
                pt[rowi * 128 + col] = f2bf(acc[m][n][r]);
            }
        }
}

// ---------------- Kernel C: combine 8 bf16 K-partials + fused loss with mirror ----------------
// 768 blocks = 32 batches x 3 tiles x 8 row-slices (16 rows each).
__global__ __launch_bounds__(256) void combine_loss(const u16* __restrict__ pg,
                                                    const float* __restrict__ T,
                                                    float* __restrict__ partials) {
    __shared__ float Gs[128][17];   // [col][row-within-slice], padded
    __shared__ float red[4];

    const int t = threadIdx.x;
    const int lane = t & 63;
    const int wid = t >> 6;
    const int bid = blockIdx.x;            // 0..767
    const int b = bid / (NTILE2 * 8);
    const int rest = bid % (NTILE2 * 8);
    const int tile = rest >> 3;
    const int q = rest & 7;                // 16-row slice
    const int ti = c2_TI[tile], tj = c2_TJ[tile];
    const bool diag = (ti == tj);
    const float invNorm = 1.0f / 33554432.0f;

    const u16* ptile = pg + (size_t)(b * NTILE2 + tile) * NKSP * 16384;
    const float* Tb = T + (size_t)b * (NCHAN * NCHAN);

    // thread tile: row r = t>>4 in [0,16), cols c0..c0+7 with c0 = (t&15)*8
    const int r = t >> 4;
    const int c0 = (t & 15) * 8;
    const int base = q * 2048 + r * 128 + c0;

    float G[8] = {};
#pragma unroll
    for (int sl = 0; sl < NKSP; ++sl) {
        bf16x8 pv = *reinterpret_cast<const bf16x8*>(ptile + sl * 16384 + base);
#pragma unroll
        for (int j = 0; j < 8; ++j) G[j] += (float)pv[j];
    }

    float s = 0.f;
    const int grow = ti * 128 + q * 16 + r;
#pragma unroll
    for (int j = 0; j < 8; ++j) {
        G[j] *= invNorm;
        const float d = Tb[grow * NCHAN + tj * 128 + c0 + j] - G[j];
        s += d * d;
        if (!diag) Gs[c0 + j][r] = G[j];
    }

    if (!diag) {
        __syncthreads();
        // mirror: element (row = tj*128+cc, col = ti*128+q*16+rr), G value = Gs[cc][rr]
        const int rr = t & 15;
        const int cc0 = t >> 4;
#pragma unroll
        for (int j = 0; j < 8; ++j) {
            const int cc = cc0 + 16 * j;
            const float d = Tb[(tj * 128 + cc) * NCHAN + ti * 128 + q * 16 + rr] - Gs[cc][rr];
            s += d * d;
        }
    }

#pragma unroll
    for (int dd = 32; dd >= 1; dd >>= 1) s += __shfl_down(s, dd);
    if (lane == 0) red[wid] = s;
    __syncthreads();
    if (t == 0) partials[bid] = red[0] + red[1] + red[2] + red[3];
}

// ---------------- Kernel D: deterministic final reduction over 768 partials ----------------
__global__ __launch_bounds__(256) void final_reduce(const float* __restrict__ partials,
                                                    float* __restrict__ out) {
    __shared__ float red[4];
    const int t = threadIdx.x;
    const int lane = t & 63;
    const int wid = t >> 6;
    float s = partials[t] + partials[t + 256] + partials[t + 512];
#pragma unroll
    for (int dd = 32; dd >= 1; dd >>= 1) s += __shfl_down(s, dd);
    if (lane == 0) red[wid] = s;
    __syncthreads();
    if (t == 0) out[0] = (red[0] + red[1] + red[2] + red[3]) * (1.0e9f / 2097152.0f);
}

extern "C" void kernel_launch(void* const* d_in, const int* in_sizes, int n_in,
                              void* d_out, int out_size, void* d_ws, size_t ws_size,
                              hipStream_t stream) {
    const float* x  = (const float*)d_in[0];           // (32,256,64,64) fp32
    const float* tg = (const float*)d_in[1];           // (32,256,256) fp32
    float* out = (float*)d_out;

    // ws layout: [0,4KiB) partials (768 f32... first 3KiB); [4KiB, +24MiB) bf16 pg; then F (64 MiB)
    float* partials = (float*)d_ws;
    u16* pg = (u16*)((char*)d_ws + 4096);
    u16* F = (u16*)((char*)d_ws + 4096 + (size_t)NBATCH * NTILE2 * NKSP * 16384 * 2);

    topk_sparsify<<<NBATCH * NCHAN, 256, 0, stream>>>(x, F);
    gram_partial<<<NBATCH * NTILE2 * NKSP, 256, 0, stream>>>(F, pg);
    combine_loss<<<NBATCH * NTILE2 * 8, 256, 0, stream>>>(pg, tg, partials);
    final_reduce<<<1, 256, 0, stream>>>(partials, out);
}